// Round 11
// baseline (289.551 us; speedup 1.0000x reference)
//
#include <hip/hip_runtime.h>

#define HW (128*128)

typedef __bf16 bf16x8 __attribute__((ext_vector_type(8)));
typedef float  float4v __attribute__((ext_vector_type(4)));
typedef float  float16v __attribute__((ext_vector_type(16)));
typedef int    int4v   __attribute__((ext_vector_type(4)));
typedef int    int2v   __attribute__((ext_vector_type(2)));

static __device__ __forceinline__ short f2bf(float f) {
    unsigned u = __float_as_uint(f);
    unsigned r = (u + 0x7FFFu + ((u >> 16) & 1u)) >> 16;
    return (short)(r & 0xFFFFu);
}
static __device__ __forceinline__ int pack2(short a, short b) {
    return (int)((unsigned short)a | ((unsigned)(unsigned short)b << 16));
}
// async global->LDS, 16B per lane; LDS dest = wave-uniform base + lane*16
static __device__ __forceinline__ void async_cp16(const void* g, void* l) {
    __builtin_amdgcn_global_load_lds(
        (const __attribute__((address_space(1))) unsigned int*)g,
        (__attribute__((address_space(3))) unsigned int*)l, 16, 0, 0);
}

// ---------------------------------------------------------------------------
// prep: weight repacks, zero buffer, h2p halo zeroing.
// W1sw/W2sw: 4-chunk XOR swizzle c^((n>>1)&3) (conv12).
// W3g: [tap][s][kh][288 n][8 k] bf16 (16B k-contiguous per (n,kh)) for direct
//      global B-frag reads of mfma_32x32x16 (lane ml=n, kh selects k-half).
// ---------------------------------------------------------------------------
__global__ __launch_bounds__(256) void prep_weights(
    const float* __restrict__ W1, const float* __restrict__ W2,
    const float* __restrict__ W3,
    short* __restrict__ W1sw, short* __restrict__ W2sw, short* __restrict__ W3g,
    char* __restrict__ h2p, int4v* __restrict__ zerobuf)
{
    int tid = blockIdx.x * 256 + threadIdx.x;
    int stride = gridDim.x * 256;
    for (int i = tid; i < 5*256*8; i += stride) {
        int e = i & 7, q = (i >> 3) & 255, s = i >> 11;
        int n = q >> 2, c = q & 3;
        int gc = c ^ ((n >> 1) & 3);
        int tap = 2*s + (gc >> 1);
        int ch = (gc & 1)*8 + e;
        float v = 0.f;
        if (tap < 9) {
            int ky = (tap*11) >> 5; int kx = tap - 3*ky;
            v = W1[((n*16 + ch)*3 + ky)*3 + kx];
        }
        W1sw[i] = f2bf(v);
    }
    for (int i = tid; i < 2*256*8; i += stride) {
        int e = i & 7, q = (i >> 3) & 255, s = i >> 11;
        int n = q >> 2, c = q & 3;
        int gc = c ^ ((n >> 1) & 3);
        int k = s*32 + gc*8 + e;
        W2sw[i] = f2bf(W2[n*64 + k]);
    }
    // W3g: flat i = ((tap*8 + s*2 + kh)*288 + n)*8 + e ; ci = s*16 + kh*8 + e
    for (int i = tid; i < 165888; i += stride) {
        int e = i & 7;
        int n = (i >> 3) % 288;
        int r2 = i / 2304;
        int kh = r2 & 1;
        int s = (r2 >> 1) & 3;
        int tap = r2 >> 3;
        int ch = n / 24, jj = n - 24*ch;
        int ci = s*16 + kh*8 + e;
        float v = 0.f;
        if (jj < 23) v = W3[((ch*23 + jj)*64 + ci)*9 + tap];
        W3g[i] = f2bf(v);
    }
    for (int i = tid; i < 64; i += stride) { int4v zz = {0,0,0,0}; zerobuf[i] = zz; }
    // h2p halo zero: 16 batches x 516 border px x 8 chunks
    for (int i = tid; i < 16*516*8; i += stride) {
        int cchunk = i & 7, pxi = (i >> 3) % 516, b = i / (516*8);
        int yy, xx;
        if (pxi < 130)      { yy = 0;   xx = pxi; }
        else if (pxi < 260) { yy = 129; xx = pxi - 130; }
        else if (pxi < 388) { yy = pxi - 260 + 1; xx = 0; }
        else                { yy = pxi - 388 + 1; xx = 129; }
        int4v zz = {0,0,0,0};
        *(int4v*)(h2p + (size_t)((b*130 + yy)*130 + xx)*128 + cchunk*16) = zz;
    }
}

// ---------------------------------------------------------------------------
// pack z with 1-px halo; zero logdet partial slots.
// ---------------------------------------------------------------------------
__global__ __launch_bounds__(256) void pack_z(
    const float* __restrict__ x, const float* __restrict__ cond,
    short* __restrict__ zp, float* __restrict__ ldslots)
{
    int id = blockIdx.x * 256 + threadIdx.x;
    if (id < 1024) ldslots[id] = 0.f;
    if (id >= 16*130*130) return;
    int b = id / 16900;
    int rem = id - b*16900;
    int yy = rem / 130;
    int xx = rem - yy*130;
    short vs[16];
    #pragma unroll
    for (int c = 0; c < 16; ++c) vs[c] = 0;
    if (yy >= 1 && yy <= 128 && xx >= 1 && xx <= 128) {
        int pix = (yy - 1)*128 + (xx - 1);
        bool frozen = ((yy + xx) & 1) == 1;
        #pragma unroll
        for (int c = 0; c < 12; ++c)
            vs[c] = f2bf(frozen ? x[(b*12 + c)*HW + pix] : 0.f);
        #pragma unroll
        for (int c = 0; c < 4; ++c)
            vs[12 + c] = f2bf(cond[(b*4 + c)*HW + pix]);
    }
    int4v lo = { pack2(vs[0],vs[1]),  pack2(vs[2],vs[3]),
                 pack2(vs[4],vs[5]),  pack2(vs[6],vs[7]) };
    int4v hi = { pack2(vs[8],vs[9]),  pack2(vs[10],vs[11]),
                 pack2(vs[12],vs[13]),pack2(vs[14],vs[15]) };
    *(int4v*)(zp + id*16)     = lo;
    *(int4v*)(zp + id*16 + 8) = hi;
}

// ---------------------------------------------------------------------------
// fused conv1 (3x3, 16->64) + conv2 (1x1, 64->64). Block = one image row.
// b = bid&15 pins batch to one XCD's L2.
// ---------------------------------------------------------------------------
__global__ __launch_bounds__(256, 4) void conv12_kernel(
    const char* __restrict__ zp, const char* __restrict__ W1sw,
    const char* __restrict__ W2sw,
    const float* __restrict__ b1, const float* __restrict__ b2,
    const char* __restrict__ zerobuf, char* __restrict__ h2p)
{
    __shared__ __align__(16) char smem[28672];
    int t = threadIdx.x;
    int lane = t & 63, w = t >> 6;
    int l15 = lane & 15, quad = lane >> 4;
    int bid = blockIdx.x;
    int b = bid & 15, y = bid >> 4;
    int chb = (w >> 1) * 32;
    int pxb = (w & 1) * 64;
    unsigned wbase = (unsigned)__builtin_amdgcn_readfirstlane(w << 10);

    int px1 = t >> 2;
    int gc1 = (t & 3) ^ ((px1 >> 1) & 3);
    int tl1 = gc1 >> 1, zoff1 = px1*32 + (gc1 & 1)*16;
    int q2 = t + 256;
    int px2 = q2 >> 2;
    int gc2 = (q2 & 3) ^ ((px2 >> 1) & 3);
    int tl2 = gc2 >> 1, zoff2 = px2*32 + (gc2 & 1)*16;

    int waddr[2], zaddr[4];
    #pragma unroll
    for (int i = 0; i < 2; ++i) {
        int n = chb + i*16 + l15;
        waddr[i] = 8192 + n*64 + ((quad ^ ((n >> 1) & 3)) << 4);
    }
    #pragma unroll
    for (int j = 0; j < 4; ++j) {
        int px = pxb + j*16 + l15;
        zaddr[j] = px*64 + ((quad ^ ((px >> 1) & 3)) << 4);
    }

    const char* zb = zp + (size_t)(b*16900)*32;
    const float4v z4 = {0.f,0.f,0.f,0.f};
    float4v acc[2][4];
    #pragma unroll
    for (int i = 0; i < 2; ++i)
        #pragma unroll
        for (int j = 0; j < 4; ++j) acc[i][j] = z4;

    for (int s = 0; s < 5; ++s) {
        __syncthreads();
        int ta = 2*s + tl1;
        const char* g1;
        if (ta < 9) { int ky = (ta*11) >> 5; int kx = ta - 3*ky;
            g1 = zb + ((y + ky)*130 + kx)*32 + zoff1; }
        else g1 = zerobuf + (lane << 4);
        async_cp16(g1, smem + wbase);
        int tb = 2*s + tl2;
        const char* g2;
        if (tb < 9) { int ky = (tb*11) >> 5; int kx = tb - 3*ky;
            g2 = zb + ((y + ky)*130 + kx)*32 + zoff2; }
        else g2 = zerobuf + (lane << 4);
        async_cp16(g2, smem + 4096 + wbase);
        async_cp16(W1sw + s*4096 + (t << 4), smem + 8192 + wbase);
        __syncthreads();
        bf16x8 aw[2];
        #pragma unroll
        for (int i = 0; i < 2; ++i) aw[i] = *(const bf16x8*)(smem + waddr[i]);
        #pragma unroll
        for (int j = 0; j < 4; ++j) {
            bf16x8 bzv = *(const bf16x8*)(smem + zaddr[j]);
            #pragma unroll
            for (int i = 0; i < 2; ++i)
                acc[i][j] = __builtin_amdgcn_mfma_f32_16x16x32_bf16(aw[i], bzv, acc[i][j], 0, 0, 0);
        }
    }
    {
        #pragma unroll
        for (int i = 0; i < 2; ++i) {
            int ch0 = chb + i*16 + quad*4;
            float bb0 = b1[ch0], bb1 = b1[ch0+1], bb2 = b1[ch0+2], bb3 = b1[ch0+3];
            #pragma unroll
            for (int j = 0; j < 4; ++j) {
                int px = pxb + j*16 + l15;
                short s0 = f2bf(fmaxf(acc[i][j][0] + bb0, 0.f));
                short s1 = f2bf(fmaxf(acc[i][j][1] + bb1, 0.f));
                short s2 = f2bf(fmaxf(acc[i][j][2] + bb2, 0.f));
                short s3 = f2bf(fmaxf(acc[i][j][3] + bb3, 0.f));
                int2v pk = { pack2(s0, s1), pack2(s2, s3) };
                *(int2v*)(smem + 12288 + px*128 + (((ch0 >> 3) ^ (px & 7)) << 4) + ((ch0 & 7) << 1)) = pk;
            }
        }
    }
    float4v acc2[2][4];
    #pragma unroll
    for (int i = 0; i < 2; ++i)
        #pragma unroll
        for (int j = 0; j < 4; ++j) acc2[i][j] = z4;
    for (int s = 0; s < 2; ++s) {
        __syncthreads();
        async_cp16(W2sw + s*4096 + (t << 4), smem + 8192 + wbase);
        __syncthreads();
        bf16x8 aw[2];
        #pragma unroll
        for (int i = 0; i < 2; ++i) aw[i] = *(const bf16x8*)(smem + waddr[i]);
        #pragma unroll
        for (int j = 0; j < 4; ++j) {
            int px = pxb + j*16 + l15;
            bf16x8 bh = *(const bf16x8*)(smem + 12288 + px*128 + (((s*4 + quad) ^ (px & 7)) << 4));
            #pragma unroll
            for (int i = 0; i < 2; ++i)
                acc2[i][j] = __builtin_amdgcn_mfma_f32_16x16x32_bf16(aw[i], bh, acc2[i][j], 0, 0, 0);
        }
    }
    __syncthreads();
    {
        #pragma unroll
        for (int i = 0; i < 2; ++i) {
            int ch0 = chb + i*16 + quad*4;
            float bb0 = b2[ch0], bb1 = b2[ch0+1], bb2 = b2[ch0+2], bb3 = b2[ch0+3];
            #pragma unroll
            for (int j = 0; j < 4; ++j) {
                int px = pxb + j*16 + l15;
                short s0 = f2bf(fmaxf(acc2[i][j][0] + bb0, 0.f));
                short s1 = f2bf(fmaxf(acc2[i][j][1] + bb1, 0.f));
                short s2 = f2bf(fmaxf(acc2[i][j][2] + bb2, 0.f));
                short s3 = f2bf(fmaxf(acc2[i][j][3] + bb3, 0.f));
                int2v pk = { pack2(s0, s1), pack2(s2, s3) };
                *(int2v*)(smem + 12288 + px*128 + (((ch0 >> 3) ^ (px & 7)) << 4) + ((ch0 & 7) << 1)) = pk;
            }
        }
    }
    __syncthreads();
    char* dst = h2p + ((size_t)(b*130 + y + 1)*130 + 1)*128;
    #pragma unroll
    for (int u = 0; u < 4; ++u) {
        int q = t + u*256;
        int px = q >> 3, g = q & 7;
        int4v v = *(const int4v*)(smem + 12288 + px*128 + ((g ^ (px & 7)) << 4));
        *(int4v*)(dst + px*128 + (g << 4)) = v;
    }
}

// ---------------------------------------------------------------------------
// RQS transform for one pixel given 23 params + x value. Returns y, adds lad.
// ---------------------------------------------------------------------------
static __device__ __forceinline__ float rqs_eval(
    const float* __restrict__ pa, float xin, bool frozen, float& ldsum)
{
    float xa = frozen ? 0.f : xin;
    float xf = frozen ? xin : 0.f;
    float xc = fminf(fmaxf(xa, -3.f), 3.f);
    bool inside = (xa >= -3.f) && (xa <= 3.f);

    float mw = pa[0];
    #pragma unroll
    for (int j = 1; j < 8; ++j) mw = fmaxf(mw, pa[j]);
    float ew[8]; float sw = 0.f;
    #pragma unroll
    for (int j = 0; j < 8; ++j) { ew[j] = __expf(pa[j] - mw); sw += ew[j]; }
    float Aw = 0.992f / sw;
    float run = 0.f, cwl = -3.f, icw = -3.f, iwid = 1.f;
    int idx = 0;
    #pragma unroll
    for (int j = 0; j < 8; ++j) {
        float wj = fmaf(Aw, ew[j], 0.001f);
        run += wj;
        float cwr = (j == 7) ? 3.f : fmaf(6.f, run, -3.f);
        if (xc >= cwl) { icw = cwl; iwid = cwr - cwl; idx = j; }
        cwl = cwr;
    }
    float mh = pa[8];
    #pragma unroll
    for (int j = 9; j < 16; ++j) mh = fmaxf(mh, pa[j]);
    float eh[8]; float sh = 0.f;
    #pragma unroll
    for (int j = 0; j < 8; ++j) { eh[j] = __expf(pa[8 + j] - mh); sh += eh[j]; }
    float Ah = 0.992f / sh;
    run = 0.f;
    float chl = -3.f, ich = 0.f, ihei = 1.f;
    #pragma unroll
    for (int j = 0; j < 8; ++j) {
        float hj = fmaf(Ah, eh[j], 0.001f);
        run += hj;
        float chr = (j == 7) ? 3.f : fmaf(6.f, run, -3.f);
        if (j == idx) { ich = chl; ihei = chr - chl; }
        chl = chr;
    }
    float v0 = 0.f, v1 = 0.f;
    bool h0 = false, h1 = false;
    #pragma unroll
    for (int j = 1; j < 8; ++j) {
        float v = pa[15 + j];
        if (j == idx)     { v0 = v; h0 = true; }
        if (j == idx + 1) { v1 = v; h1 = true; }
    }
    float sp0 = (v0 > 15.f) ? v0 : __logf(1.f + __expf(v0));
    float sp1 = (v1 > 15.f) ? v1 : __logf(1.f + __expf(v1));
    float d0 = h0 ? (0.001f + sp0) : 1.f;
    float d1 = h1 ? (0.001f + sp1) : 1.f;

    float dl = ihei / iwid;
    float th = (xc - icw) / iwid;
    float omt = 1.f - th;
    float t1 = th * omt;
    float num = ihei * (dl*th*th + d0*t1);
    float den = dl + (d0 + d1 - 2.f*dl)*t1;
    float yv = ich + num/den;
    float dnum = dl*dl*(d1*th*th + 2.f*dl*t1 + d0*omt*omt);
    float lad = __logf(dnum) - 2.f*__logf(den);

    ldsum += inside ? lad : 0.f;
    return xf + (inside ? yv : xa);
}

// ---------------------------------------------------------------------------
// conv3 (3x3, 64 -> 276 pad 288) fused with RQS — NO LDS IN K-LOOP.
// Block = 256 thr (4 waves = 4 px-subs of 32), tile 128 px x 96 col (one cg).
// Grid 6144 = 16b x 3cg x 128y, b = bid&15 XCD-pinned.
// Both MFMA operands read DIRECTLY from global: A 16B/lane from h2p (lines
// fully consumed across s-substeps + tap shifts -> L1-resident), B 16B/lane
// from k-contiguous W3g (L2-resident 331KB, identical across all 4 waves ->
// L1-hot). Zero barriers in K-loop; loads pipeline via vmcnt.
// Wave acc = 3 x float16 = 48 VGPRs -> 4 waves/SIMD (launch_bounds cap 128).
// ---------------------------------------------------------------------------
__global__ __launch_bounds__(256, 4) void conv3_rqs_kernel(
    const char* __restrict__ h2p, const char* __restrict__ W3g,
    const float* __restrict__ b3, const float* __restrict__ x,
    float* __restrict__ out, float* __restrict__ ldslots)
{
    __shared__ __align__(16) float scr[64*100];   // 25.6 KB epilogue scratch
    int t = threadIdx.x;
    int lane = t & 63, w = t >> 6;
    int ml = lane & 31, kh = lane >> 5;
    int bid = blockIdx.x;
    int b = bid & 15;
    int r0 = bid >> 4;
    int cg = r0 % 3;
    int y = r0 / 3;

    const char* h2pb = h2p + (size_t)(b*130)*130*128;
    const float16v z16 = {0.f,0.f,0.f,0.f,0.f,0.f,0.f,0.f,
                          0.f,0.f,0.f,0.f,0.f,0.f,0.f,0.f};
    float16v acc[3];
    #pragma unroll
    for (int j = 0; j < 3; ++j) acc[j] = z16;

    int px0 = w << 5;                         // wave's pixel base
    int abase = (px0 + ml)*128 + (kh << 4);   // per-lane A offset within row
    int bnoff = (cg*96 + ml) << 4;            // per-lane B n-offset (bytes)

    for (int tap = 0; tap < 9; ++tap) {
        int ty = (tap*11) >> 5;
        int tx = tap - 3*ty;
        const char* arow = h2pb + ((y + ty)*130 + tx)*128 + abase;
        const char* bb = W3g + (((tap << 3) + kh)*288 << 4) + bnoff;
        #pragma unroll
        for (int s = 0; s < 4; ++s) {
            bf16x8 av = *(const bf16x8*)(arow + (s << 5));
            const char* bp = bb + s*9216;     // s*2*288*16
            #pragma unroll
            for (int j = 0; j < 3; ++j) {
                bf16x8 bv = *(const bf16x8*)(bp + (j << 9));
                acc[j] = __builtin_amdgcn_mfma_f32_32x32x16_bf16(av, bv, acc[j], 0, 0, 0);
            }
        }
    }

    // -------- epilogue: 2 rounds (64 px x 96 col), 1 task/thread ------------
    // C/D layout (m74/m101, R10-verified): col = ml, row = (r&3)+8*(r>>2)+4*kh
    float ldsum = 0.f;
    int pxl = t & 63;
    int chl = t >> 6;            // 0..3
    int ch = cg*4 + chl;
    const float* bb3 = b3 + ch*23;

    #pragma unroll
    for (int rnd = 0; rnd < 2; ++rnd) {
        if ((w >> 1) == rnd) {   // waves 0,1 own px 0-63; waves 2,3 own 64-127
            int pxbase = (w & 1) << 5;
            #pragma unroll
            for (int j = 0; j < 3; ++j)
                #pragma unroll
                for (int r = 0; r < 16; ++r) {
                    int row = pxbase + (r & 3) + ((r >> 2) << 3) + (kh << 2);
                    scr[row*100 + (j << 5) + ml] = acc[j][r];
                }
        }
        __syncthreads();
        const float* P = scr + pxl*100 + chl*24;
        float pa[23];
        {
            float pr[24];
            *(float4v*)&pr[0]  = *(const float4v*)(P);
            *(float4v*)&pr[4]  = *(const float4v*)(P + 4);
            *(float4v*)&pr[8]  = *(const float4v*)(P + 8);
            *(float4v*)&pr[12] = *(const float4v*)(P + 12);
            *(float4v*)&pr[16] = *(const float4v*)(P + 16);
            *(float4v*)&pr[20] = *(const float4v*)(P + 20);
            #pragma unroll
            for (int j = 0; j < 23; ++j) pa[j] = pr[j] + bb3[j];
        }
        int pxg = (rnd << 6) + pxl;
        int gidx = ((b*12 + ch) << 14) + (y << 7) + pxg;
        float xin = x[gidx];
        bool frozen = ((y + pxg) & 1) == 1;
        out[gidx] = rqs_eval(pa, xin, frozen, ldsum);
        __syncthreads();
    }
    #pragma unroll
    for (int off = 32; off > 0; off >>= 1)
        ldsum += __shfl_down(ldsum, off, 64);
    if (lane == 0) atomicAdd(ldslots + b*64 + (y & 63), ldsum);
}

// ---------------------------------------------------------------------------
// final logdet reduce: 16 blocks x 64 lanes.
// ---------------------------------------------------------------------------
__global__ __launch_bounds__(64) void logdet_reduce(
    const float* __restrict__ ldslots, const float* __restrict__ ld_in,
    float* __restrict__ ldout)
{
    int b = blockIdx.x;
    int lane = threadIdx.x;
    float s = ldslots[b*64 + lane];
    #pragma unroll
    for (int off = 32; off > 0; off >>= 1)
        s += __shfl_down(s, off, 64);
    if (lane == 0) ldout[b] = ld_in[b] + s;
}

// ---------------------------------------------------------------------------
extern "C" void kernel_launch(void* const* d_in, const int* in_sizes, int n_in,
                              void* d_out, int out_size, void* d_ws, size_t ws_size,
                              hipStream_t stream)
{
    (void)in_sizes; (void)n_in; (void)out_size; (void)ws_size;
    const float* x    = (const float*)d_in[0];
    const float* ld   = (const float*)d_in[1];
    const float* cond = (const float*)d_in[2];
    const float* W1   = (const float*)d_in[3];
    const float* b1   = (const float*)d_in[4];
    const float* W2   = (const float*)d_in[5];
    const float* b2   = (const float*)d_in[6];
    const float* W3   = (const float*)d_in[7];
    const float* b3   = (const float*)d_in[8];
    float* out = (float*)d_out;
    char* ws = (char*)d_ws;

    short* zp     = (short*)(ws);              //  8,652,800 B
    char*  h2p    = ws + 8652800;              // 34,611,200 B
    short* W1sw   = (short*)(ws + 43264000);   //     20,480 B
    short* W2sw   = (short*)(ws + 43284480);   //      8,192 B
    short* W3g    = (short*)(ws + 43292672);   //    331,776 B
    char*  zerob  = ws + 43624448;             //      1,024 B
    float* ldslots= (float*)(ws + 43625472);   //      4,096 B
    float* ldout  = out + 12*HW*16;

    prep_weights<<<dim3(256), dim3(256), 0, stream>>>(
        W1, W2, W3, W1sw, W2sw, W3g, h2p, (int4v*)zerob);
    pack_z<<<dim3(1057), dim3(256), 0, stream>>>(x, cond, zp, ldslots);
    conv12_kernel<<<dim3(2048), dim3(256), 0, stream>>>(
        (const char*)zp, (const char*)W1sw, (const char*)W2sw, b1, b2,
        (const char*)zerob, h2p);
    conv3_rqs_kernel<<<dim3(6144), dim3(256), 0, stream>>>(
        (const char*)h2p, (const char*)W3g, b3, x, out, ldslots);
    logdet_reduce<<<dim3(16), dim3(64), 0, stream>>>(ldslots, ld, ldout);
}

// Round 12
// 199.819 us; speedup vs baseline: 1.4491x; 1.4491x over previous
//
#include <hip/hip_runtime.h>

#define HW (128*128)

typedef __bf16 bf16x8 __attribute__((ext_vector_type(8)));
typedef float  float4v __attribute__((ext_vector_type(4)));
typedef int    int4v   __attribute__((ext_vector_type(4)));
typedef int    int2v   __attribute__((ext_vector_type(2)));

static __device__ __forceinline__ short f2bf(float f) {
    unsigned u = __float_as_uint(f);
    unsigned r = (u + 0x7FFFu + ((u >> 16) & 1u)) >> 16;
    return (short)(r & 0xFFFFu);
}
static __device__ __forceinline__ int pack2(short a, short b) {
    return (int)((unsigned short)a | ((unsigned)(unsigned short)b << 16));
}
// async global->LDS, 16B per lane; LDS dest = wave-uniform base + lane*16
static __device__ __forceinline__ void async_cp16(const void* g, void* l) {
    __builtin_amdgcn_global_load_lds(
        (const __attribute__((address_space(1))) unsigned int*)g,
        (__attribute__((address_space(3))) unsigned int*)l, 16, 0, 0);
}

// ---------------------------------------------------------------------------
// prep: weight repacks, zero buffer, h2p halo zeroing.
// W1sw/W2sw: 4-chunk XOR swizzle c^((n>>1)&3) (conv12).
// W3g: [tap][ks][quad][288 n][8 e] bf16 — B-frag of mfma_f32_16x16x32_bf16
//      read direct from global: lane (n=l15+16j, quad) reads 16B = its 8
//      k-elems k = ks*32 + quad*8 + e.
// ---------------------------------------------------------------------------
__global__ __launch_bounds__(256) void prep_weights(
    const float* __restrict__ W1, const float* __restrict__ W2,
    const float* __restrict__ W3,
    short* __restrict__ W1sw, short* __restrict__ W2sw, short* __restrict__ W3g,
    char* __restrict__ h2p, int4v* __restrict__ zerobuf)
{
    int tid = blockIdx.x * 256 + threadIdx.x;
    int stride = gridDim.x * 256;
    for (int i = tid; i < 5*256*8; i += stride) {
        int e = i & 7, q = (i >> 3) & 255, s = i >> 11;
        int n = q >> 2, c = q & 3;
        int gc = c ^ ((n >> 1) & 3);
        int tap = 2*s + (gc >> 1);
        int ch = (gc & 1)*8 + e;
        float v = 0.f;
        if (tap < 9) {
            int ky = (tap*11) >> 5; int kx = tap - 3*ky;
            v = W1[((n*16 + ch)*3 + ky)*3 + kx];
        }
        W1sw[i] = f2bf(v);
    }
    for (int i = tid; i < 2*256*8; i += stride) {
        int e = i & 7, q = (i >> 3) & 255, s = i >> 11;
        int n = q >> 2, c = q & 3;
        int gc = c ^ ((n >> 1) & 3);
        int k = s*32 + gc*8 + e;
        W2sw[i] = f2bf(W2[n*64 + k]);
    }
    // W3g: flat i = ((tap*8 + ks*4 + quad)*288 + n)*8 + e
    for (int i = tid; i < 165888; i += stride) {
        int e = i & 7;
        int n = (i >> 3) % 288;
        int r2 = i / 2304;
        int quad = r2 & 3;
        int ks = (r2 >> 2) & 1;
        int tap = r2 >> 3;
        int ch = n / 24, jj = n - 24*ch;
        int kk = ks*32 + quad*8 + e;
        float v = 0.f;
        if (jj < 23) v = W3[((ch*23 + jj)*64 + kk)*9 + tap];
        W3g[i] = f2bf(v);
    }
    for (int i = tid; i < 64; i += stride) { int4v zz = {0,0,0,0}; zerobuf[i] = zz; }
    // h2p halo zero: 16 batches x 516 border px x 8 chunks
    for (int i = tid; i < 16*516*8; i += stride) {
        int cchunk = i & 7, pxi = (i >> 3) % 516, b = i / (516*8);
        int yy, xx;
        if (pxi < 130)      { yy = 0;   xx = pxi; }
        else if (pxi < 260) { yy = 129; xx = pxi - 130; }
        else if (pxi < 388) { yy = pxi - 260 + 1; xx = 0; }
        else                { yy = pxi - 388 + 1; xx = 129; }
        int4v zz = {0,0,0,0};
        *(int4v*)(h2p + (size_t)((b*130 + yy)*130 + xx)*128 + cchunk*16) = zz;
    }
}

// ---------------------------------------------------------------------------
// pack z with 1-px halo; zero logdet partial slots.
// ---------------------------------------------------------------------------
__global__ __launch_bounds__(256) void pack_z(
    const float* __restrict__ x, const float* __restrict__ cond,
    short* __restrict__ zp, float* __restrict__ ldslots)
{
    int id = blockIdx.x * 256 + threadIdx.x;
    if (id < 1024) ldslots[id] = 0.f;
    if (id >= 16*130*130) return;
    int b = id / 16900;
    int rem = id - b*16900;
    int yy = rem / 130;
    int xx = rem - yy*130;
    short vs[16];
    #pragma unroll
    for (int c = 0; c < 16; ++c) vs[c] = 0;
    if (yy >= 1 && yy <= 128 && xx >= 1 && xx <= 128) {
        int pix = (yy - 1)*128 + (xx - 1);
        bool frozen = ((yy + xx) & 1) == 1;
        #pragma unroll
        for (int c = 0; c < 12; ++c)
            vs[c] = f2bf(frozen ? x[(b*12 + c)*HW + pix] : 0.f);
        #pragma unroll
        for (int c = 0; c < 4; ++c)
            vs[12 + c] = f2bf(cond[(b*4 + c)*HW + pix]);
    }
    int4v lo = { pack2(vs[0],vs[1]),  pack2(vs[2],vs[3]),
                 pack2(vs[4],vs[5]),  pack2(vs[6],vs[7]) };
    int4v hi = { pack2(vs[8],vs[9]),  pack2(vs[10],vs[11]),
                 pack2(vs[12],vs[13]),pack2(vs[14],vs[15]) };
    *(int4v*)(zp + id*16)     = lo;
    *(int4v*)(zp + id*16 + 8) = hi;
}

// ---------------------------------------------------------------------------
// fused conv1 (3x3, 16->64) + conv2 (1x1, 64->64). Block = one image row.
// b = bid&15 pins batch to one XCD's L2.
// ---------------------------------------------------------------------------
__global__ __launch_bounds__(256, 4) void conv12_kernel(
    const char* __restrict__ zp, const char* __restrict__ W1sw,
    const char* __restrict__ W2sw,
    const float* __restrict__ b1, const float* __restrict__ b2,
    const char* __restrict__ zerobuf, char* __restrict__ h2p)
{
    __shared__ __align__(16) char smem[28672];
    int t = threadIdx.x;
    int lane = t & 63, w = t >> 6;
    int l15 = lane & 15, quad = lane >> 4;
    int bid = blockIdx.x;
    int b = bid & 15, y = bid >> 4;
    int chb = (w >> 1) * 32;
    int pxb = (w & 1) * 64;
    unsigned wbase = (unsigned)__builtin_amdgcn_readfirstlane(w << 10);

    int px1 = t >> 2;
    int gc1 = (t & 3) ^ ((px1 >> 1) & 3);
    int tl1 = gc1 >> 1, zoff1 = px1*32 + (gc1 & 1)*16;
    int q2 = t + 256;
    int px2 = q2 >> 2;
    int gc2 = (q2 & 3) ^ ((px2 >> 1) & 3);
    int tl2 = gc2 >> 1, zoff2 = px2*32 + (gc2 & 1)*16;

    int waddr[2], zaddr[4];
    #pragma unroll
    for (int i = 0; i < 2; ++i) {
        int n = chb + i*16 + l15;
        waddr[i] = 8192 + n*64 + ((quad ^ ((n >> 1) & 3)) << 4);
    }
    #pragma unroll
    for (int j = 0; j < 4; ++j) {
        int px = pxb + j*16 + l15;
        zaddr[j] = px*64 + ((quad ^ ((px >> 1) & 3)) << 4);
    }

    const char* zb = zp + (size_t)(b*16900)*32;
    const float4v z4 = {0.f,0.f,0.f,0.f};
    float4v acc[2][4];
    #pragma unroll
    for (int i = 0; i < 2; ++i)
        #pragma unroll
        for (int j = 0; j < 4; ++j) acc[i][j] = z4;

    for (int s = 0; s < 5; ++s) {
        __syncthreads();
        int ta = 2*s + tl1;
        const char* g1;
        if (ta < 9) { int ky = (ta*11) >> 5; int kx = ta - 3*ky;
            g1 = zb + ((y + ky)*130 + kx)*32 + zoff1; }
        else g1 = zerobuf + (lane << 4);
        async_cp16(g1, smem + wbase);
        int tb = 2*s + tl2;
        const char* g2;
        if (tb < 9) { int ky = (tb*11) >> 5; int kx = tb - 3*ky;
            g2 = zb + ((y + ky)*130 + kx)*32 + zoff2; }
        else g2 = zerobuf + (lane << 4);
        async_cp16(g2, smem + 4096 + wbase);
        async_cp16(W1sw + s*4096 + (t << 4), smem + 8192 + wbase);
        __syncthreads();
        bf16x8 aw[2];
        #pragma unroll
        for (int i = 0; i < 2; ++i) aw[i] = *(const bf16x8*)(smem + waddr[i]);
        #pragma unroll
        for (int j = 0; j < 4; ++j) {
            bf16x8 bzv = *(const bf16x8*)(smem + zaddr[j]);
            #pragma unroll
            for (int i = 0; i < 2; ++i)
                acc[i][j] = __builtin_amdgcn_mfma_f32_16x16x32_bf16(aw[i], bzv, acc[i][j], 0, 0, 0);
        }
    }
    {
        #pragma unroll
        for (int i = 0; i < 2; ++i) {
            int ch0 = chb + i*16 + quad*4;
            float bb0 = b1[ch0], bb1 = b1[ch0+1], bb2 = b1[ch0+2], bb3 = b1[ch0+3];
            #pragma unroll
            for (int j = 0; j < 4; ++j) {
                int px = pxb + j*16 + l15;
                short s0 = f2bf(fmaxf(acc[i][j][0] + bb0, 0.f));
                short s1 = f2bf(fmaxf(acc[i][j][1] + bb1, 0.f));
                short s2 = f2bf(fmaxf(acc[i][j][2] + bb2, 0.f));
                short s3 = f2bf(fmaxf(acc[i][j][3] + bb3, 0.f));
                int2v pk = { pack2(s0, s1), pack2(s2, s3) };
                *(int2v*)(smem + 12288 + px*128 + (((ch0 >> 3) ^ (px & 7)) << 4) + ((ch0 & 7) << 1)) = pk;
            }
        }
    }
    float4v acc2[2][4];
    #pragma unroll
    for (int i = 0; i < 2; ++i)
        #pragma unroll
        for (int j = 0; j < 4; ++j) acc2[i][j] = z4;
    for (int s = 0; s < 2; ++s) {
        __syncthreads();
        async_cp16(W2sw + s*4096 + (t << 4), smem + 8192 + wbase);
        __syncthreads();
        bf16x8 aw[2];
        #pragma unroll
        for (int i = 0; i < 2; ++i) aw[i] = *(const bf16x8*)(smem + waddr[i]);
        #pragma unroll
        for (int j = 0; j < 4; ++j) {
            int px = pxb + j*16 + l15;
            bf16x8 bh = *(const bf16x8*)(smem + 12288 + px*128 + (((s*4 + quad) ^ (px & 7)) << 4));
            #pragma unroll
            for (int i = 0; i < 2; ++i)
                acc2[i][j] = __builtin_amdgcn_mfma_f32_16x16x32_bf16(aw[i], bh, acc2[i][j], 0, 0, 0);
        }
    }
    __syncthreads();
    {
        #pragma unroll
        for (int i = 0; i < 2; ++i) {
            int ch0 = chb + i*16 + quad*4;
            float bb0 = b2[ch0], bb1 = b2[ch0+1], bb2 = b2[ch0+2], bb3 = b2[ch0+3];
            #pragma unroll
            for (int j = 0; j < 4; ++j) {
                int px = pxb + j*16 + l15;
                short s0 = f2bf(fmaxf(acc2[i][j][0] + bb0, 0.f));
                short s1 = f2bf(fmaxf(acc2[i][j][1] + bb1, 0.f));
                short s2 = f2bf(fmaxf(acc2[i][j][2] + bb2, 0.f));
                short s3 = f2bf(fmaxf(acc2[i][j][3] + bb3, 0.f));
                int2v pk = { pack2(s0, s1), pack2(s2, s3) };
                *(int2v*)(smem + 12288 + px*128 + (((ch0 >> 3) ^ (px & 7)) << 4) + ((ch0 & 7) << 1)) = pk;
            }
        }
    }
    __syncthreads();
    char* dst = h2p + ((size_t)(b*130 + y + 1)*130 + 1)*128;
    #pragma unroll
    for (int u = 0; u < 4; ++u) {
        int q = t + u*256;
        int px = q >> 3, g = q & 7;
        int4v v = *(const int4v*)(smem + 12288 + px*128 + ((g ^ (px & 7)) << 4));
        *(int4v*)(dst + px*128 + (g << 4)) = v;
    }
}

// ---------------------------------------------------------------------------
// RQS transform for one pixel given 23 params + x value. Returns y, adds lad.
// ---------------------------------------------------------------------------
static __device__ __forceinline__ float rqs_eval(
    const float* __restrict__ pa, float xin, bool frozen, float& ldsum)
{
    float xa = frozen ? 0.f : xin;
    float xf = frozen ? xin : 0.f;
    float xc = fminf(fmaxf(xa, -3.f), 3.f);
    bool inside = (xa >= -3.f) && (xa <= 3.f);

    float mw = pa[0];
    #pragma unroll
    for (int j = 1; j < 8; ++j) mw = fmaxf(mw, pa[j]);
    float ew[8]; float sw = 0.f;
    #pragma unroll
    for (int j = 0; j < 8; ++j) { ew[j] = __expf(pa[j] - mw); sw += ew[j]; }
    float Aw = 0.992f / sw;
    float run = 0.f, cwl = -3.f, icw = -3.f, iwid = 1.f;
    int idx = 0;
    #pragma unroll
    for (int j = 0; j < 8; ++j) {
        float wj = fmaf(Aw, ew[j], 0.001f);
        run += wj;
        float cwr = (j == 7) ? 3.f : fmaf(6.f, run, -3.f);
        if (xc >= cwl) { icw = cwl; iwid = cwr - cwl; idx = j; }
        cwl = cwr;
    }
    float mh = pa[8];
    #pragma unroll
    for (int j = 9; j < 16; ++j) mh = fmaxf(mh, pa[j]);
    float eh[8]; float sh = 0.f;
    #pragma unroll
    for (int j = 0; j < 8; ++j) { eh[j] = __expf(pa[8 + j] - mh); sh += eh[j]; }
    float Ah = 0.992f / sh;
    run = 0.f;
    float chl = -3.f, ich = 0.f, ihei = 1.f;
    #pragma unroll
    for (int j = 0; j < 8; ++j) {
        float hj = fmaf(Ah, eh[j], 0.001f);
        run += hj;
        float chr = (j == 7) ? 3.f : fmaf(6.f, run, -3.f);
        if (j == idx) { ich = chl; ihei = chr - chl; }
        chl = chr;
    }
    float v0 = 0.f, v1 = 0.f;
    bool h0 = false, h1 = false;
    #pragma unroll
    for (int j = 1; j < 8; ++j) {
        float v = pa[15 + j];
        if (j == idx)     { v0 = v; h0 = true; }
        if (j == idx + 1) { v1 = v; h1 = true; }
    }
    float sp0 = (v0 > 15.f) ? v0 : __logf(1.f + __expf(v0));
    float sp1 = (v1 > 15.f) ? v1 : __logf(1.f + __expf(v1));
    float d0 = h0 ? (0.001f + sp0) : 1.f;
    float d1 = h1 ? (0.001f + sp1) : 1.f;

    float dl = ihei / iwid;
    float th = (xc - icw) / iwid;
    float omt = 1.f - th;
    float t1 = th * omt;
    float num = ihei * (dl*th*th + d0*t1);
    float den = dl + (d0 + d1 - 2.f*dl)*t1;
    float yv = ich + num/den;
    float dnum = dl*dl*(d1*th*th + 2.f*dl*t1 + d0*omt*omt);
    float lad = __logf(dnum) - 2.f*__logf(den);

    ldsum += inside ? lad : 0.f;
    return xf + (inside ? yv : xa);
}

// ---------------------------------------------------------------------------
// conv3 (3x3, 64 -> 276 pad 288) fused with RQS — HYBRID operand paths.
// Block = 192 thr (3 waves), tile 64 px x 144 col; wave = 64px x 48col,
// acc[4][3] = 48 VGPRs (16x16x32 MFMA). Grid 8192 = 16b x 128y x 2h x 2cg,
// b = bid&15 XCD-pinned.
// A: 3 halo'd h2p row-windows (72px ea) staged ONCE (27.6KB, XOR-swizzled),
//    ONE barrier; K-loop reads via ds_read_b128 (LDS pipe).
// B: direct global 16B frag loads from k-contiguous W3g (L1/L2 pipe).
// Traffic split: LDS 4KB + L1 3KB per 12 MFMA -> ceilings 45%/60% vs R7's
// all-LDS 30% and R11's all-L1 19% (both HW-validated by rocprof).
// ---------------------------------------------------------------------------
__global__ __launch_bounds__(192, 4) void conv3_rqs_kernel(
    const char* __restrict__ h2p, const char* __restrict__ W3g,
    const float* __restrict__ b3, const float* __restrict__ x,
    float* __restrict__ out, float* __restrict__ ldslots)
{
    __shared__ __align__(16) char smem[27648];
    // staging: 3 rows x 72 px x 128 B (p 66..71 = harmless overfetch pad)
    // epilogue (aliased): scr 32 px x 148 floats = 18,944 B
    int t = threadIdx.x;
    int lane = t & 63, w = t >> 6;     // w = col-group of 48 (0..2)
    int l15 = lane & 15, quad = lane >> 4;
    int bid = blockIdx.x;
    int b = bid & 15;
    int r = bid >> 4;                  // 0..511
    int chalf = r & 1;
    int h = (r >> 1) & 1;
    int y = r >> 2;

    // ---- stage A once: 1728 chunks (3 rows x 72 px x 8) over 192 thr ----
    const char* h2pb = h2p + (size_t)(b*130)*130*128;
    int colLo = h*64;
    #pragma unroll
    for (int ii = 0; ii < 9; ++ii) {
        int q = t + ii*192;
        int row = q / 576;
        int rem = q - row*576;
        int p = rem >> 3, cs = rem & 7;
        int cg = cs ^ (p & 7);
        const char* g = h2pb + (((y + row)*130 + colLo + p) << 7) + (cg << 4);
        async_cp16(g, smem + (unsigned)__builtin_amdgcn_readfirstlane(
                                 (w << 10) + ii*3072) + (lane << 4));
    }
    __syncthreads();

    const float4v z4 = {0.f,0.f,0.f,0.f};
    float4v acc[4][3];
    #pragma unroll
    for (int i = 0; i < 4; ++i)
        #pragma unroll
        for (int j = 0; j < 3; ++j) acc[i][j] = z4;

    int bcol = chalf*144 + w*48 + l15;     // global B col for j=0

    for (int tap = 0; tap < 9; ++tap) {
        int ty = (tap*11) >> 5;
        int tx = tap - 3*ty;
        int rowbase = ty*9216;
        #pragma unroll
        for (int ks = 0; ks < 2; ++ks) {
            bf16x8 av[4];
            #pragma unroll
            for (int i = 0; i < 4; ++i) {
                int p = i*16 + l15 + tx;
                av[i] = *(const bf16x8*)(smem + rowbase + (p << 7)
                         + ((((ks << 2) + quad) ^ (p & 7)) << 4));
            }
            const char* bp = W3g
                + ((((tap*2 + ks)*4 + quad)*288 + bcol) << 4);
            #pragma unroll
            for (int j = 0; j < 3; ++j) {
                bf16x8 bv = *(const bf16x8*)(bp + (j << 8));
                #pragma unroll
                for (int i = 0; i < 4; ++i)
                    acc[i][j] = __builtin_amdgcn_mfma_f32_16x16x32_bf16(av[i], bv, acc[i][j], 0, 0, 0);
            }
        }
    }
    __syncthreads();   // all staged-A reads done -> alias LDS for epilogue

    // -------- epilogue: 2 rounds (32 px x 144 col), 1 task/thread ----------
    // C/D (m89): out px = i*16 + quad*4 + reg, col/channel = l15
    float* scr = (float*)smem;   // [32 px][148]
    float ldsum = 0.f;
    int pxl = t & 31;
    int chl = t >> 5;            // 0..5
    int ch = chalf*6 + chl;
    const float* bb3 = b3 + ch*23;

    #pragma unroll
    for (int rnd = 0; rnd < 2; ++rnd) {
        #pragma unroll
        for (int i2 = 0; i2 < 2; ++i2) {
            int i = rnd*2 + i2;
            #pragma unroll
            for (int j = 0; j < 3; ++j)
                #pragma unroll
                for (int rr = 0; rr < 4; ++rr)
                    scr[(i2*16 + quad*4 + rr)*148 + w*48 + j*16 + l15] = acc[i][j][rr];
        }
        __syncthreads();
        const float* P = scr + pxl*148 + chl*24;
        float pa[23];
        {
            float pr[24];
            *(float4v*)&pr[0]  = *(const float4v*)(P);
            *(float4v*)&pr[4]  = *(const float4v*)(P + 4);
            *(float4v*)&pr[8]  = *(const float4v*)(P + 8);
            *(float4v*)&pr[12] = *(const float4v*)(P + 12);
            *(float4v*)&pr[16] = *(const float4v*)(P + 16);
            *(float4v*)&pr[20] = *(const float4v*)(P + 20);
            #pragma unroll
            for (int j = 0; j < 23; ++j) pa[j] = pr[j] + bb3[j];
        }
        int pxg = h*64 + rnd*32 + pxl;
        int gidx = ((b*12 + ch) << 14) + (y << 7) + pxg;
        float xin = x[gidx];
        bool frozen = ((y + pxg) & 1) == 1;
        out[gidx] = rqs_eval(pa, xin, frozen, ldsum);
        __syncthreads();
    }
    #pragma unroll
    for (int off = 32; off > 0; off >>= 1)
        ldsum += __shfl_down(ldsum, off, 64);
    if (lane == 0) atomicAdd(ldslots + b*64 + (r & 63), ldsum);
}

// ---------------------------------------------------------------------------
// final logdet reduce: 16 blocks x 64 lanes.
// ---------------------------------------------------------------------------
__global__ __launch_bounds__(64) void logdet_reduce(
    const float* __restrict__ ldslots, const float* __restrict__ ld_in,
    float* __restrict__ ldout)
{
    int b = blockIdx.x;
    int lane = threadIdx.x;
    float s = ldslots[b*64 + lane];
    #pragma unroll
    for (int off = 32; off > 0; off >>= 1)
        s += __shfl_down(s, off, 64);
    if (lane == 0) ldout[b] = ld_in[b] + s;
}

// ---------------------------------------------------------------------------
extern "C" void kernel_launch(void* const* d_in, const int* in_sizes, int n_in,
                              void* d_out, int out_size, void* d_ws, size_t ws_size,
                              hipStream_t stream)
{
    (void)in_sizes; (void)n_in; (void)out_size; (void)ws_size;
    const float* x    = (const float*)d_in[0];
    const float* ld   = (const float*)d_in[1];
    const float* cond = (const float*)d_in[2];
    const float* W1   = (const float*)d_in[3];
    const float* b1   = (const float*)d_in[4];
    const float* W2   = (const float*)d_in[5];
    const float* b2   = (const float*)d_in[6];
    const float* W3   = (const float*)d_in[7];
    const float* b3   = (const float*)d_in[8];
    float* out = (float*)d_out;
    char* ws = (char*)d_ws;

    short* zp     = (short*)(ws);              //  8,652,800 B
    char*  h2p    = ws + 8652800;              // 34,611,200 B
    short* W1sw   = (short*)(ws + 43264000);   //     20,480 B
    short* W2sw   = (short*)(ws + 43284480);   //      8,192 B
    short* W3g    = (short*)(ws + 43292672);   //    331,776 B
    char*  zerob  = ws + 43624448;             //      1,024 B
    float* ldslots= (float*)(ws + 43625472);   //      4,096 B
    float* ldout  = out + 12*HW*16;

    prep_weights<<<dim3(256), dim3(256), 0, stream>>>(
        W1, W2, W3, W1sw, W2sw, W3g, h2p, (int4v*)zerob);
    pack_z<<<dim3(1057), dim3(256), 0, stream>>>(x, cond, zp, ldslots);
    conv12_kernel<<<dim3(2048), dim3(256), 0, stream>>>(
        (const char*)zp, (const char*)W1sw, (const char*)W2sw, b1, b2,
        (const char*)zerob, h2p);
    conv3_rqs_kernel<<<dim3(8192), dim3(192), 0, stream>>>(
        (const char*)h2p, (const char*)W3g, b3, x, out, ldslots);
    logdet_reduce<<<dim3(16), dim3(64), 0, stream>>>(ldslots, ld, ldout);
}